// Round 14
// baseline (432.601 us; speedup 1.0000x reference)
//
#include <hip/hip_runtime.h>
#include <hip/hip_fp16.h>

#define NN 200000
#define NE 6400000
#define FIN 256
#define HID 16
#define NC 40
#define NBKT 782        // ceil(NN/256) dst-buckets of 256 nodes
#define NCHUNK 2048     // microchunks
#define EPC 3125        // edges per microchunk: 2048*3125 = 6.4M exact
#define CPT 8           // chunks per thread in btotal/cscan (2048/256)
#define SC_CHUNKS 2     // chunks per scatter block, processed SEQUENTIALLY
#define SC_BLOCKS (NCHUNK / SC_CHUNKS)  // 1024
#define STAGE_CAP 9472  // bucket stage capacity (mean 8192, ~14 sigma)

// ---- 1. per-microchunk coarse histogram; ALSO persists raw counts (cnt_g) ----
__global__ __launch_bounds__(256) void k_chist(const int* __restrict__ dst,
                                               int* __restrict__ hist_g,
                                               int* __restrict__ cnt_g) {
    __shared__ int sh[NBKT];
    int c = blockIdx.x;
    for (int j = threadIdx.x; j < NBKT; j += 256) sh[j] = 0;
    __syncthreads();
    int beg = c * EPC;
    for (int e = beg + threadIdx.x; e < beg + EPC; e += 256)
        atomicAdd(&sh[dst[e] >> 8], 1);
    __syncthreads();
    for (int j = threadIdx.x; j < NBKT; j += 256) {
        int v = sh[j];
        hist_g[c * NBKT + j] = v;
        cnt_g[c * NBKT + j] = v;
    }
}

// ---- 2. bucket totals: block per bucket, tree reduce over 2048 chunks ----
__global__ __launch_bounds__(256) void k_btotal(const int* __restrict__ hist_g,
                                                int* __restrict__ totals) {
    __shared__ int sm[256];
    int b = blockIdx.x, t = threadIdx.x;
    int s = 0;
#pragma unroll
    for (int j = 0; j < CPT; ++j)
        s += hist_g[(t * CPT + j) * NBKT + b];
    sm[t] = s;
    __syncthreads();
    for (int off = 128; off > 0; off >>= 1) {
        if (t < off) sm[t] += sm[t + off];
        __syncthreads();
    }
    if (t == 0) totals[b] = sm[0];
}

// ---- 3. exclusive scan of 782 totals -> binBase ----
__global__ __launch_bounds__(1024) void k_bscan(const int* __restrict__ totals,
                                                int* __restrict__ binBase) {
    __shared__ int sm[1024];
    int t = threadIdx.x;
    int v = (t < NBKT) ? totals[t] : 0;
    sm[t] = v;
    __syncthreads();
    for (int off = 1; off < 1024; off <<= 1) {
        int x = (t >= off) ? sm[t - off] : 0;
        __syncthreads();
        sm[t] += x;
        __syncthreads();
    }
    if (t < NBKT) binBase[t] = sm[t] - v;
    if (t == 0) binBase[NBKT] = NE;
}

// ---- 4. per-bucket scan over 2048 microchunks, in place: hist -> cursor bases ----
__global__ __launch_bounds__(256) void k_cscan(int* __restrict__ hist_g,
                                               const int* __restrict__ binBase) {
    __shared__ int sm[256];
    int b = blockIdx.x, t = threadIdx.x;
    int loc[CPT];
    int s = 0;
#pragma unroll
    for (int j = 0; j < CPT; ++j) {
        loc[j] = hist_g[(t * CPT + j) * NBKT + b];
        s += loc[j];
    }
    sm[t] = s;
    __syncthreads();
    for (int off = 1; off < 256; off <<= 1) {
        int x = (t >= off) ? sm[t - off] : 0;
        __syncthreads();
        sm[t] += x;
        __syncthreads();
    }
    int base = binBase[b] + sm[t] - s;
#pragma unroll
    for (int j = 0; j < CPT; ++j) {
        hist_g[(t * CPT + j) * NBKT + b] = base;
        base += loc[j];
    }
}

// ---- 5. coarse scatter: counts from cnt_g (no recount pass), bucket-id array
// filled at scan time (no binary search). LDS 38.5KB -> 4 blocks/CU kept.
// 2 chunks sequential per block (keeps full-line write ownership from r13).
__global__ __launch_bounds__(256) void k_cscatter(const int* __restrict__ src,
                                                  const int* __restrict__ dst,
                                                  const float* __restrict__ w,
                                                  const int* __restrict__ coff,
                                                  const int* __restrict__ cnt_g,
                                                  int2* __restrict__ ebuf) {
    __shared__ int2 srec[EPC];                 // 25000 B sorted stage
    __shared__ unsigned short sbkt[EPC + 2];   // 6254 B bucket id per slot
    __shared__ int scur[NBKT];                 // rank cursors
    __shared__ int sgb[NBKT];                  // global base - local base
    __shared__ int sm[256];
    int t = threadIdx.x;
    for (int cc = 0; cc < SC_CHUNKS; ++cc) {
        int c = blockIdx.x * SC_CHUNKS + cc;
        // local scan of this chunk's counts (from cnt_g; no dst re-read)
        int l[4];
        int s = 0;
#pragma unroll
        for (int q = 0; q < 4; ++q) {
            int j = t * 4 + q;
            l[q] = (j < NBKT) ? cnt_g[c * NBKT + j] : 0;
            s += l[q];
        }
        sm[t] = s;
        __syncthreads();
        for (int off = 1; off < 256; off <<= 1) {
            int x = (t >= off) ? sm[t - off] : 0;
            __syncthreads();
            sm[t] += x;
            __syncthreads();
        }
        int base = sm[t] - s;
#pragma unroll
        for (int q = 0; q < 4; ++q) {
            int j = t * 4 + q;
            if (j < NBKT) {
                scur[j] = base;
                sgb[j]  = coff[c * NBKT + j] - base;
                for (int u = 0; u < l[q]; ++u)       // fill bucket ids at scan
                    sbkt[base + u] = (unsigned short)j;
            }
            base += l[q];
        }
        __syncthreads();
        // rank & scatter into sorted LDS; record = {src | dl<<18, w}
        int beg = c * EPC;
        for (int e = beg + t; e < beg + EPC; e += 256) {
            int d = dst[e];
            int k = atomicAdd(&scur[d >> 8], 1);
            srec[k] = make_int2(src[e] | ((d & 255) << 18), __float_as_int(w[e]));
        }
        __syncthreads();
        // linear write-out, no search
        for (int k = t; k < EPC; k += 256)
            ebuf[sgb[sbkt[k]] + k] = srec[k];
        __syncthreads();   // protect LDS before next chunk reuses it
    }
}

// ---- 6. fused per-bucket: stage once -> counts+deg -> scan -> dinv/row_start ->
//         rank -> direct ranked global store ----
__global__ __launch_bounds__(256) void k_bsort(const int* __restrict__ binBase,
                                               int2* __restrict__ ebuf,
                                               float* __restrict__ dinv,
                                               int* __restrict__ row_start) {
    __shared__ int2 stage[STAGE_CAP];   // 75776 B
    __shared__ float sdeg[256];
    __shared__ int scnt[256];           // counts -> reused as rank cursors
    __shared__ int ssc[256];
    int b = blockIdx.x, t = threadIdx.x;
    scnt[t] = 0;
    sdeg[t] = 1.0f;  // self-loop weight
    __syncthreads();
    int beg = binBase[b], end = binBase[b + 1];
    int cnt = end - beg;
    for (int j = t; j < cnt; j += 256) {
        int2 r = ebuf[beg + j];
        stage[j] = r;
        int dl = (r.x >> 18) & 255;
        atomicAdd(&scnt[dl], 1);
        atomicAdd(&sdeg[dl], __int_as_float(r.y));
    }
    __syncthreads();
    int node = b * 256 + t;
    if (node < NN) dinv[node] = rsqrtf(sdeg[t]);   // deg >= 1 always
    int v = scnt[t];
    ssc[t] = v;
    __syncthreads();
    for (int off = 1; off < 256; off <<= 1) {
        int x = (t >= off) ? ssc[t - off] : 0;
        __syncthreads();
        ssc[t] += x;
        __syncthreads();
    }
    int excl = ssc[t] - v;
    if (node < NN) row_start[node] = beg + excl;
    if (b == NBKT - 1 && t == 0) row_start[NN] = NE;
    scnt[t] = excl;
    __syncthreads();
    for (int j = t; j < cnt; j += 256) {
        int2 r = stage[j];
        int dl = (r.x >> 18) & 255;
        int k = atomicAdd(&scnt[dl], 1);
        ebuf[beg + k] = r;
    }
}

// ---- 7. h' = fp16( dinv[row] * (x @ W1) ), full-line (64B) batched x loads ----
__global__ __launch_bounds__(256) void k_gemm1(const float* __restrict__ x,
                                               const float* __restrict__ W1,
                                               const float* __restrict__ dinv,
                                               __half2* __restrict__ hp) {
    int row = blockIdx.x * 256 + threadIdx.x;
    if (row >= NN) return;
    float acc[HID];
#pragma unroll
    for (int f = 0; f < HID; ++f) acc[f] = 0.0f;
    const float4* x4 = reinterpret_cast<const float4*>(x + (size_t)row * FIN);
    for (int kk = 0; kk < FIN / 4; kk += 4) {
        float4 v0 = x4[kk], v1 = x4[kk + 1], v2 = x4[kk + 2], v3 = x4[kk + 3];
        float xs[16] = { v0.x, v0.y, v0.z, v0.w, v1.x, v1.y, v1.z, v1.w,
                         v2.x, v2.y, v2.z, v2.w, v3.x, v3.y, v3.z, v3.w };
        int kbase = kk * 4;
#pragma unroll
        for (int j = 0; j < 16; ++j) {
            int k = kbase + j;
#pragma unroll
            for (int f = 0; f < HID; ++f)
                acc[f] = fmaf(xs[j], W1[k * HID + f], acc[f]);
        }
    }
    float di = dinv[row];
    __half2 o[8];
#pragma unroll
    for (int j = 0; j < 8; ++j)
        o[j] = __floats2half2_rn(acc[2*j] * di, acc[2*j+1] * di);
    float4* st = reinterpret_cast<float4*>(hp + (size_t)row * 8);
    st[0] = *reinterpret_cast<float4*>(&o[0]);
    st[1] = *reinterpret_cast<float4*>(&o[4]);
}

// fp16 row (2 float4s = 8 half2 = 16 features) FMA into f32 accumulators
__device__ __forceinline__ void fma_row16(const float4 u0, const float4 u1, float nv,
                                          float4& a0, float4& a1, float4& a2, float4& a3) {
    const __half2* ha = reinterpret_cast<const __half2*>(&u0);
    const __half2* hb = reinterpret_cast<const __half2*>(&u1);
    float2 f;
    f = __half22float2(ha[0]); a0.x = fmaf(f.x, nv, a0.x); a0.y = fmaf(f.y, nv, a0.y);
    f = __half22float2(ha[1]); a0.z = fmaf(f.x, nv, a0.z); a0.w = fmaf(f.y, nv, a0.w);
    f = __half22float2(ha[2]); a1.x = fmaf(f.x, nv, a1.x); a1.y = fmaf(f.y, nv, a1.y);
    f = __half22float2(ha[3]); a1.z = fmaf(f.x, nv, a1.z); a1.w = fmaf(f.y, nv, a1.w);
    f = __half22float2(hb[0]); a2.x = fmaf(f.x, nv, a2.x); a2.y = fmaf(f.y, nv, a2.y);
    f = __half22float2(hb[1]); a2.z = fmaf(f.x, nv, a2.z); a2.w = fmaf(f.y, nv, a2.w);
    f = __half22float2(hb[2]); a3.x = fmaf(f.x, nv, a3.x); a3.y = fmaf(f.y, nv, a3.y);
    f = __half22float2(hb[3]); a3.z = fmaf(f.x, nv, a3.z); a3.w = fmaf(f.y, nv, a3.w);
}

union H2F2 { __half2 h[2]; float2 f; };

// ---- 8. gather layer 1, 4 edges in flight ----
__global__ __launch_bounds__(256) void k_gather1(const int* __restrict__ row_start,
                                                 const int2* __restrict__ edges,
                                                 const __half2* __restrict__ hp,
                                                 const float* __restrict__ dinv,
                                                 const float* __restrict__ b1,
                                                 __half2* __restrict__ h1p) {
    int t = blockIdx.x * 256 + threadIdx.x;   // grid exact: 4*NN threads
    int i = t >> 2;
    int sub = t & 3;
    int beg = row_start[i];
    int end = row_start[i + 1];
    float4 a0 = make_float4(0.f,0.f,0.f,0.f), a1 = a0, a2 = a0, a3 = a0;
    if (sub == 0) {  // self-loop seed: h'[i]
        const float4* r4 = reinterpret_cast<const float4*>(hp + (size_t)i * 8);
        fma_row16(r4[0], r4[1], 1.0f, a0, a1, a2, a3);
    }
    int p = beg + sub;
    for (; p + 12 < end; p += 16) {   // 4 edges, 8 row loads outstanding
        int2 e0 = edges[p], e1 = edges[p + 4], e2 = edges[p + 8], e3 = edges[p + 12];
        const float4* r0 = reinterpret_cast<const float4*>(hp + (size_t)(e0.x & 0x3FFFF) * 8);
        const float4* r1 = reinterpret_cast<const float4*>(hp + (size_t)(e1.x & 0x3FFFF) * 8);
        const float4* r2 = reinterpret_cast<const float4*>(hp + (size_t)(e2.x & 0x3FFFF) * 8);
        const float4* r3 = reinterpret_cast<const float4*>(hp + (size_t)(e3.x & 0x3FFFF) * 8);
        float4 u0a = r0[0], u0b = r0[1];
        float4 u1a = r1[0], u1b = r1[1];
        float4 u2a = r2[0], u2b = r2[1];
        float4 u3a = r3[0], u3b = r3[1];
        fma_row16(u0a, u0b, __int_as_float(e0.y), a0, a1, a2, a3);
        fma_row16(u1a, u1b, __int_as_float(e1.y), a0, a1, a2, a3);
        fma_row16(u2a, u2b, __int_as_float(e2.y), a0, a1, a2, a3);
        fma_row16(u3a, u3b, __int_as_float(e3.y), a0, a1, a2, a3);
    }
    for (; p < end; p += 4) {
        int2 ev = edges[p];
        const float4* r4 = reinterpret_cast<const float4*>(hp + (size_t)(ev.x & 0x3FFFF) * 8);
        fma_row16(r4[0], r4[1], __int_as_float(ev.y), a0, a1, a2, a3);
    }
#pragma unroll
    for (int m = 1; m <= 2; m <<= 1) {
        a0.x += __shfl_xor(a0.x, m); a0.y += __shfl_xor(a0.y, m);
        a0.z += __shfl_xor(a0.z, m); a0.w += __shfl_xor(a0.w, m);
        a1.x += __shfl_xor(a1.x, m); a1.y += __shfl_xor(a1.y, m);
        a1.z += __shfl_xor(a1.z, m); a1.w += __shfl_xor(a1.w, m);
        a2.x += __shfl_xor(a2.x, m); a2.y += __shfl_xor(a2.y, m);
        a2.z += __shfl_xor(a2.z, m); a2.w += __shfl_xor(a2.w, m);
        a3.x += __shfl_xor(a3.x, m); a3.y += __shfl_xor(a3.y, m);
        a3.z += __shfl_xor(a3.z, m); a3.w += __shfl_xor(a3.w, m);
    }
    float4 q = (sub == 0) ? a0 : (sub == 1) ? a1 : (sub == 2) ? a2 : a3;
    float di = dinv[i];
    float4 bb = reinterpret_cast<const float4*>(b1)[sub];
    q.x = di * fmaxf(fmaf(di, q.x, bb.x), 0.f);
    q.y = di * fmaxf(fmaf(di, q.y, bb.y), 0.f);
    q.z = di * fmaxf(fmaf(di, q.z, bb.z), 0.f);
    q.w = di * fmaxf(fmaf(di, q.w, bb.w), 0.f);
    H2F2 pk;
    pk.h[0] = __floats2half2_rn(q.x, q.y);
    pk.h[1] = __floats2half2_rn(q.z, q.w);
    reinterpret_cast<float2*>(h1p + (size_t)i * 8)[sub] = pk.f;
}

// ---- 9. gather layer 2 fused with GEMM2, 4 edges in flight ----
__global__ __launch_bounds__(256) void k_gather2(const int* __restrict__ row_start,
                                                 const int2* __restrict__ edges,
                                                 const __half2* __restrict__ h1p,
                                                 const float* __restrict__ dinv,
                                                 const float* __restrict__ W2,
                                                 const float* __restrict__ b2,
                                                 float* __restrict__ out) {
    __shared__ float sW2[HID * NC];
    __shared__ float sb2[NC];
    {
        int tt = threadIdx.x;
        for (int j = tt; j < HID * NC; j += 256) sW2[j] = W2[j];
        if (tt < NC) sb2[tt] = b2[tt];
    }
    __syncthreads();
    int t = blockIdx.x * 256 + threadIdx.x;
    int i = t >> 2;
    int sub = t & 3;
    int beg = row_start[i];
    int end = row_start[i + 1];
    float4 a0 = make_float4(0.f,0.f,0.f,0.f), a1 = a0, a2 = a0, a3 = a0;
    if (sub == 0) {
        const float4* r4 = reinterpret_cast<const float4*>(h1p + (size_t)i * 8);
        fma_row16(r4[0], r4[1], 1.0f, a0, a1, a2, a3);
    }
    int p = beg + sub;
    for (; p + 12 < end; p += 16) {
        int2 e0 = edges[p], e1 = edges[p + 4], e2 = edges[p + 8], e3 = edges[p + 12];
        const float4* r0 = reinterpret_cast<const float4*>(h1p + (size_t)(e0.x & 0x3FFFF) * 8);
        const float4* r1 = reinterpret_cast<const float4*>(h1p + (size_t)(e1.x & 0x3FFFF) * 8);
        const float4* r2 = reinterpret_cast<const float4*>(h1p + (size_t)(e2.x & 0x3FFFF) * 8);
        const float4* r3 = reinterpret_cast<const float4*>(h1p + (size_t)(e3.x & 0x3FFFF) * 8);
        float4 u0a = r0[0], u0b = r0[1];
        float4 u1a = r1[0], u1b = r1[1];
        float4 u2a = r2[0], u2b = r2[1];
        float4 u3a = r3[0], u3b = r3[1];
        fma_row16(u0a, u0b, __int_as_float(e0.y), a0, a1, a2, a3);
        fma_row16(u1a, u1b, __int_as_float(e1.y), a0, a1, a2, a3);
        fma_row16(u2a, u2b, __int_as_float(e2.y), a0, a1, a2, a3);
        fma_row16(u3a, u3b, __int_as_float(e3.y), a0, a1, a2, a3);
    }
    for (; p < end; p += 4) {
        int2 ev = edges[p];
        const float4* r4 = reinterpret_cast<const float4*>(h1p + (size_t)(ev.x & 0x3FFFF) * 8);
        fma_row16(r4[0], r4[1], __int_as_float(ev.y), a0, a1, a2, a3);
    }
#pragma unroll
    for (int m = 1; m <= 2; m <<= 1) {
        a0.x += __shfl_xor(a0.x, m); a0.y += __shfl_xor(a0.y, m);
        a0.z += __shfl_xor(a0.z, m); a0.w += __shfl_xor(a0.w, m);
        a1.x += __shfl_xor(a1.x, m); a1.y += __shfl_xor(a1.y, m);
        a1.z += __shfl_xor(a1.z, m); a1.w += __shfl_xor(a1.w, m);
        a2.x += __shfl_xor(a2.x, m); a2.y += __shfl_xor(a2.y, m);
        a2.z += __shfl_xor(a2.z, m); a2.w += __shfl_xor(a2.w, m);
        a3.x += __shfl_xor(a3.x, m); a3.y += __shfl_xor(a3.y, m);
        a3.z += __shfl_xor(a3.z, m); a3.w += __shfl_xor(a3.w, m);
    }
    float di = dinv[i];
    float av[HID] = { a0.x, a0.y, a0.z, a0.w, a1.x, a1.y, a1.z, a1.w,
                      a2.x, a2.y, a2.z, a2.w, a3.x, a3.y, a3.z, a3.w };
#pragma unroll
    for (int k = 0; k < HID; ++k) av[k] *= di;
    float* op = out + (size_t)i * NC + sub * 10;
#pragma unroll
    for (int c = 0; c < 10; ++c) {
        int col = sub * 10 + c;
        float s = sb2[col];
#pragma unroll
        for (int k = 0; k < HID; ++k)
            s = fmaf(av[k], sW2[k * NC + col], s);
        op[c] = s;
    }
}

// ---- launch ----
extern "C" void kernel_launch(void* const* d_in, const int* in_sizes, int n_in,
                              void* d_out, int out_size, void* d_ws, size_t ws_size,
                              hipStream_t stream) {
    const float* x  = (const float*)d_in[0];
    const int*   ei = (const int*)d_in[1];
    const float* w  = (const float*)d_in[2];
    const float* W1 = (const float*)d_in[3];
    const float* b1 = (const float*)d_in[4];
    const float* W2 = (const float*)d_in[5];
    const float* b2 = (const float*)d_in[6];
    float* out = (float*)d_out;

    const int* src = ei;
    const int* dst = ei + NE;

    // workspace layout (4B words), ~72 MB (<= 79.2MB proven available).
    // hp (fp16 rows) shares its region with hist_g (dead after k_cscatter;
    // hp first written by k_gemm1, later in stream order). cnt_g is separate.
    char* wsb = (char*)d_ws;
    float*   dinv      = (float*)  (wsb);                      // 200064
    int*     row_start = (int*)    (wsb + 200064LL * 4);       // 200064 (NN+1 used)
    int*     totals    = (int*)    (wsb + 400128LL * 4);       // 1024
    int*     binBase   = (int*)    (wsb + 401152LL * 4);       // 1024 (NBKT+1 used)
    int2*    ebuf      = (int2*)   (wsb + 402176LL * 4);       // NE int2 = 12.8M words
    __half2* hp        = (__half2*)(wsb + 13202176LL * 4);     // NN*8 half2 (1.6M words)
    int*     hist_g    = (int*)    (wsb + 13202176LL * 4);     // aliases hp region
    __half2* h1p       = (__half2*)(wsb + 14803776LL * 4);     // NN*8 half2 (1.6M words)
    int*     cnt_g     = (int*)    (wsb + 16405376LL * 4);     // 2048*782 = 1,601,536 words

    const int BN = (NN + 255) / 256;   // 782
    const int BG = (4 * NN) / 256;     // 3125 exact

    k_chist   <<<NCHUNK, 256, 0, stream>>>(dst, hist_g, cnt_g);
    k_btotal  <<<NBKT, 256, 0, stream>>>(hist_g, totals);
    k_bscan   <<<1, 1024, 0, stream>>>(totals, binBase);
    k_cscan   <<<NBKT, 256, 0, stream>>>(hist_g, binBase);
    k_cscatter<<<SC_BLOCKS, 256, 0, stream>>>(src, dst, w, hist_g, cnt_g, ebuf);
    k_bsort   <<<NBKT, 256, 0, stream>>>(binBase, ebuf, dinv, row_start);
    k_gemm1   <<<BN, 256, 0, stream>>>(x, W1, dinv, hp);
    k_gather1 <<<BG, 256, 0, stream>>>(row_start, ebuf, hp, dinv, b1, h1p);
    k_gather2 <<<BG, 256, 0, stream>>>(row_start, ebuf, h1p, dinv, W2, b2, out);
}

// Round 15
// 413.617 us; speedup vs baseline: 1.0459x; 1.0459x over previous
//
#include <hip/hip_runtime.h>
#include <hip/hip_fp16.h>

#define NN 200000
#define NE 6400000
#define FIN 256
#define HID 16
#define NC 40
#define NBKT 782        // ceil(NN/256) dst-buckets of 256 nodes
#define NCHUNK 2048     // microchunks
#define EPC 3125        // edges per microchunk: 2048*3125 = 6.4M exact
#define CPT 8           // chunks per thread in btotal/cscan (2048/256)
#define SC_CHUNKS 2     // chunks per scatter block, processed SEQUENTIALLY
#define SC_BLOCKS (NCHUNK / SC_CHUNKS)  // 1024
#define STAGE_CAP 9472  // bucket stage capacity (mean 8192, ~14 sigma)

// ---- 1. per-microchunk coarse histogram; ALSO persists raw counts (cnt_g) ----
__global__ __launch_bounds__(256) void k_chist(const int* __restrict__ dst,
                                               int* __restrict__ hist_g,
                                               int* __restrict__ cnt_g) {
    __shared__ int sh[NBKT];
    int c = blockIdx.x;
    for (int j = threadIdx.x; j < NBKT; j += 256) sh[j] = 0;
    __syncthreads();
    int beg = c * EPC;
    for (int e = beg + threadIdx.x; e < beg + EPC; e += 256)
        atomicAdd(&sh[dst[e] >> 8], 1);
    __syncthreads();
    for (int j = threadIdx.x; j < NBKT; j += 256) {
        int v = sh[j];
        hist_g[c * NBKT + j] = v;
        cnt_g[c * NBKT + j] = v;
    }
}

// ---- 2. bucket totals: block per bucket, tree reduce over 2048 chunks ----
__global__ __launch_bounds__(256) void k_btotal(const int* __restrict__ hist_g,
                                                int* __restrict__ totals) {
    __shared__ int sm[256];
    int b = blockIdx.x, t = threadIdx.x;
    int s = 0;
#pragma unroll
    for (int j = 0; j < CPT; ++j)
        s += hist_g[(t * CPT + j) * NBKT + b];
    sm[t] = s;
    __syncthreads();
    for (int off = 128; off > 0; off >>= 1) {
        if (t < off) sm[t] += sm[t + off];
        __syncthreads();
    }
    if (t == 0) totals[b] = sm[0];
}

// ---- 3. exclusive scan of 782 totals -> binBase ----
__global__ __launch_bounds__(1024) void k_bscan(const int* __restrict__ totals,
                                                int* __restrict__ binBase) {
    __shared__ int sm[1024];
    int t = threadIdx.x;
    int v = (t < NBKT) ? totals[t] : 0;
    sm[t] = v;
    __syncthreads();
    for (int off = 1; off < 1024; off <<= 1) {
        int x = (t >= off) ? sm[t - off] : 0;
        __syncthreads();
        sm[t] += x;
        __syncthreads();
    }
    if (t < NBKT) binBase[t] = sm[t] - v;
    if (t == 0) binBase[NBKT] = NE;
}

// ---- 4. per-bucket scan over 2048 microchunks, in place: hist -> cursor bases ----
__global__ __launch_bounds__(256) void k_cscan(int* __restrict__ hist_g,
                                               const int* __restrict__ binBase) {
    __shared__ int sm[256];
    int b = blockIdx.x, t = threadIdx.x;
    int loc[CPT];
    int s = 0;
#pragma unroll
    for (int j = 0; j < CPT; ++j) {
        loc[j] = hist_g[(t * CPT + j) * NBKT + b];
        s += loc[j];
    }
    sm[t] = s;
    __syncthreads();
    for (int off = 1; off < 256; off <<= 1) {
        int x = (t >= off) ? sm[t - off] : 0;
        __syncthreads();
        sm[t] += x;
        __syncthreads();
    }
    int base = binBase[b] + sm[t] - s;
#pragma unroll
    for (int j = 0; j < CPT; ++j) {
        hist_g[(t * CPT + j) * NBKT + b] = base;
        base += loc[j];
    }
}

// ---- 5. coarse scatter: counts from cnt_g, bucket-id array at scan time ----
__global__ __launch_bounds__(256) void k_cscatter(const int* __restrict__ src,
                                                  const int* __restrict__ dst,
                                                  const float* __restrict__ w,
                                                  const int* __restrict__ coff,
                                                  const int* __restrict__ cnt_g,
                                                  int2* __restrict__ ebuf) {
    __shared__ int2 srec[EPC];                 // 25000 B sorted stage
    __shared__ unsigned short sbkt[EPC + 2];   // 6254 B bucket id per slot
    __shared__ int scur[NBKT];                 // rank cursors
    __shared__ int sgb[NBKT];                  // global base - local base
    __shared__ int sm[256];
    int t = threadIdx.x;
    for (int cc = 0; cc < SC_CHUNKS; ++cc) {
        int c = blockIdx.x * SC_CHUNKS + cc;
        int l[4];
        int s = 0;
#pragma unroll
        for (int q = 0; q < 4; ++q) {
            int j = t * 4 + q;
            l[q] = (j < NBKT) ? cnt_g[c * NBKT + j] : 0;
            s += l[q];
        }
        sm[t] = s;
        __syncthreads();
        for (int off = 1; off < 256; off <<= 1) {
            int x = (t >= off) ? sm[t - off] : 0;
            __syncthreads();
            sm[t] += x;
            __syncthreads();
        }
        int base = sm[t] - s;
#pragma unroll
        for (int q = 0; q < 4; ++q) {
            int j = t * 4 + q;
            if (j < NBKT) {
                scur[j] = base;
                sgb[j]  = coff[c * NBKT + j] - base;
                for (int u = 0; u < l[q]; ++u)
                    sbkt[base + u] = (unsigned short)j;
            }
            base += l[q];
        }
        __syncthreads();
        int beg = c * EPC;
        for (int e = beg + t; e < beg + EPC; e += 256) {
            int d = dst[e];
            int k = atomicAdd(&scur[d >> 8], 1);
            srec[k] = make_int2(src[e] | ((d & 255) << 18), __float_as_int(w[e]));
        }
        __syncthreads();
        for (int k = t; k < EPC; k += 256)
            ebuf[sgb[sbkt[k]] + k] = srec[k];
        __syncthreads();
    }
}

// ---- 6. fused per-bucket: stage once -> counts+deg -> scan -> dinv/row_start ->
//         rank -> direct ranked global store ----
__global__ __launch_bounds__(256) void k_bsort(const int* __restrict__ binBase,
                                               int2* __restrict__ ebuf,
                                               float* __restrict__ dinv,
                                               int* __restrict__ row_start) {
    __shared__ int2 stage[STAGE_CAP];   // 75776 B
    __shared__ float sdeg[256];
    __shared__ int scnt[256];
    __shared__ int ssc[256];
    int b = blockIdx.x, t = threadIdx.x;
    scnt[t] = 0;
    sdeg[t] = 1.0f;  // self-loop weight
    __syncthreads();
    int beg = binBase[b], end = binBase[b + 1];
    int cnt = end - beg;
    for (int j = t; j < cnt; j += 256) {
        int2 r = ebuf[beg + j];
        stage[j] = r;
        int dl = (r.x >> 18) & 255;
        atomicAdd(&scnt[dl], 1);
        atomicAdd(&sdeg[dl], __int_as_float(r.y));
    }
    __syncthreads();
    int node = b * 256 + t;
    if (node < NN) dinv[node] = rsqrtf(sdeg[t]);   // deg >= 1 always
    int v = scnt[t];
    ssc[t] = v;
    __syncthreads();
    for (int off = 1; off < 256; off <<= 1) {
        int x = (t >= off) ? ssc[t - off] : 0;
        __syncthreads();
        ssc[t] += x;
        __syncthreads();
    }
    int excl = ssc[t] - v;
    if (node < NN) row_start[node] = beg + excl;
    if (b == NBKT - 1 && t == 0) row_start[NN] = NE;
    scnt[t] = excl;
    __syncthreads();
    for (int j = t; j < cnt; j += 256) {
        int2 r = stage[j];
        int dl = (r.x >> 18) & 255;
        int k = atomicAdd(&scnt[dl], 1);
        ebuf[beg + k] = r;
    }
}

// ---- 7. h' = fp16( dinv[row] * (x @ W1) ), full-line (64B) batched x loads ----
__global__ __launch_bounds__(256) void k_gemm1(const float* __restrict__ x,
                                               const float* __restrict__ W1,
                                               const float* __restrict__ dinv,
                                               __half2* __restrict__ hp) {
    int row = blockIdx.x * 256 + threadIdx.x;
    if (row >= NN) return;
    float acc[HID];
#pragma unroll
    for (int f = 0; f < HID; ++f) acc[f] = 0.0f;
    const float4* x4 = reinterpret_cast<const float4*>(x + (size_t)row * FIN);
    for (int kk = 0; kk < FIN / 4; kk += 4) {
        float4 v0 = x4[kk], v1 = x4[kk + 1], v2 = x4[kk + 2], v3 = x4[kk + 3];
        float xs[16] = { v0.x, v0.y, v0.z, v0.w, v1.x, v1.y, v1.z, v1.w,
                         v2.x, v2.y, v2.z, v2.w, v3.x, v3.y, v3.z, v3.w };
        int kbase = kk * 4;
#pragma unroll
        for (int j = 0; j < 16; ++j) {
            int k = kbase + j;
#pragma unroll
            for (int f = 0; f < HID; ++f)
                acc[f] = fmaf(xs[j], W1[k * HID + f], acc[f]);
        }
    }
    float di = dinv[row];
    __half2 o[8];
#pragma unroll
    for (int j = 0; j < 8; ++j)
        o[j] = __floats2half2_rn(acc[2*j] * di, acc[2*j+1] * di);
    float4* st = reinterpret_cast<float4*>(hp + (size_t)row * 8);
    st[0] = *reinterpret_cast<float4*>(&o[0]);
    st[1] = *reinterpret_cast<float4*>(&o[4]);
}

// fp16 half-row (16B = 8 features) FMA into two float4 accumulators
__device__ __forceinline__ void fma_row8(const float4 u, float nv,
                                         float4& a, float4& b) {
    const __half2* h = reinterpret_cast<const __half2*>(&u);
    float2 f;
    f = __half22float2(h[0]); a.x = fmaf(f.x, nv, a.x); a.y = fmaf(f.y, nv, a.y);
    f = __half22float2(h[1]); a.z = fmaf(f.x, nv, a.z); a.w = fmaf(f.y, nv, a.w);
    f = __half22float2(h[2]); b.x = fmaf(f.x, nv, b.x); b.y = fmaf(f.y, nv, b.y);
    f = __half22float2(h[3]); b.z = fmaf(f.x, nv, b.z); b.w = fmaf(f.y, nv, b.w);
}

union H4F4 { __half2 h[4]; float4 f; };

// ---- 8. gather layer 1: 8 lanes/node, lane-PAIRS share each edge so the two
// adjacent 16B halves of a 32B row are loaded by adjacent lanes in ONE
// instruction -> coalesced to a single 32B L2 transaction per edge. ----
__global__ __launch_bounds__(256) void k_gather1(const int* __restrict__ row_start,
                                                 const int2* __restrict__ edges,
                                                 const __half2* __restrict__ hp,
                                                 const float* __restrict__ dinv,
                                                 const float* __restrict__ b1,
                                                 __half2* __restrict__ h1p) {
    int t = blockIdx.x * 256 + threadIdx.x;   // grid exact: 8*NN threads
    int i = t >> 3;
    int l3 = t & 7;
    int q = l3 >> 1;      // pair 0..3: edge subset
    int half = l3 & 1;    // which 16B half of the row this lane loads
    int beg = row_start[i];
    int end = row_start[i + 1];
    const float4* hpb = reinterpret_cast<const float4*>(hp);  // row i half h -> [i*2+h]
    float4 a = make_float4(0.f,0.f,0.f,0.f), b = a;
    if (q == 0)   // self-loop seed: h'[i] (weight 1 in folded form)
        fma_row8(hpb[(size_t)i * 2 + half], 1.0f, a, b);
    int p = beg + q;
    for (; p + 12 < end; p += 16) {   // 4 edges in flight per lane
        int2 e0 = edges[p], e1 = edges[p + 4], e2 = edges[p + 8], e3 = edges[p + 12];
        float4 u0 = hpb[(size_t)(e0.x & 0x3FFFF) * 2 + half];
        float4 u1 = hpb[(size_t)(e1.x & 0x3FFFF) * 2 + half];
        float4 u2 = hpb[(size_t)(e2.x & 0x3FFFF) * 2 + half];
        float4 u3 = hpb[(size_t)(e3.x & 0x3FFFF) * 2 + half];
        fma_row8(u0, __int_as_float(e0.y), a, b);
        fma_row8(u1, __int_as_float(e1.y), a, b);
        fma_row8(u2, __int_as_float(e2.y), a, b);
        fma_row8(u3, __int_as_float(e3.y), a, b);
    }
    for (; p < end; p += 4) {
        int2 ev = edges[p];
        float4 u = hpb[(size_t)(ev.x & 0x3FFFF) * 2 + half];
        fma_row8(u, __int_as_float(ev.y), a, b);
    }
    // reduce across the 4 pairs (lanes differing in bits 1,2)
#pragma unroll
    for (int m = 2; m <= 4; m <<= 1) {
        a.x += __shfl_xor(a.x, m); a.y += __shfl_xor(a.y, m);
        a.z += __shfl_xor(a.z, m); a.w += __shfl_xor(a.w, m);
        b.x += __shfl_xor(b.x, m); b.y += __shfl_xor(b.y, m);
        b.z += __shfl_xor(b.z, m); b.w += __shfl_xor(b.w, m);
    }
    float di = dinv[i];
    float4 b1a = reinterpret_cast<const float4*>(b1)[half * 2];
    float4 b1b = reinterpret_cast<const float4*>(b1)[half * 2 + 1];
    a.x = di * fmaxf(fmaf(di, a.x, b1a.x), 0.f);
    a.y = di * fmaxf(fmaf(di, a.y, b1a.y), 0.f);
    a.z = di * fmaxf(fmaf(di, a.z, b1a.z), 0.f);
    a.w = di * fmaxf(fmaf(di, a.w, b1a.w), 0.f);
    b.x = di * fmaxf(fmaf(di, b.x, b1b.x), 0.f);
    b.y = di * fmaxf(fmaf(di, b.y, b1b.y), 0.f);
    b.z = di * fmaxf(fmaf(di, b.z, b1b.z), 0.f);
    b.w = di * fmaxf(fmaf(di, b.w, b1b.w), 0.f);
    if (q == 0) {   // pair 0's two lanes write the two 16B halves
        H4F4 pk;
        pk.h[0] = __floats2half2_rn(a.x, a.y);
        pk.h[1] = __floats2half2_rn(a.z, a.w);
        pk.h[2] = __floats2half2_rn(b.x, b.y);
        pk.h[3] = __floats2half2_rn(b.z, b.w);
        reinterpret_cast<float4*>(h1p)[(size_t)i * 2 + half] = pk.f;
    }
}

// ---- 9. gather layer 2 fused with GEMM2, 8 lanes/node pair scheme.
// Pair q computes output cols [q*10, q*10+10): each lane partial-dots its
// 8 features, xor-1 combines the halves, lanes write 5 cols each. ----
__global__ __launch_bounds__(256) void k_gather2(const int* __restrict__ row_start,
                                                 const int2* __restrict__ edges,
                                                 const __half2* __restrict__ h1p,
                                                 const float* __restrict__ dinv,
                                                 const float* __restrict__ W2,
                                                 const float* __restrict__ b2,
                                                 float* __restrict__ out) {
    __shared__ float sW2[HID * NC];
    __shared__ float sb2[NC];
    {
        int tt = threadIdx.x;
        for (int j = tt; j < HID * NC; j += 256) sW2[j] = W2[j];
        if (tt < NC) sb2[tt] = b2[tt];
    }
    __syncthreads();
    int t = blockIdx.x * 256 + threadIdx.x;   // grid exact: 8*NN threads
    int i = t >> 3;
    int l3 = t & 7;
    int q = l3 >> 1;
    int half = l3 & 1;
    int beg = row_start[i];
    int end = row_start[i + 1];
    const float4* hpb = reinterpret_cast<const float4*>(h1p);
    float4 a = make_float4(0.f,0.f,0.f,0.f), b = a;
    if (q == 0)
        fma_row8(hpb[(size_t)i * 2 + half], 1.0f, a, b);
    int p = beg + q;
    for (; p + 12 < end; p += 16) {
        int2 e0 = edges[p], e1 = edges[p + 4], e2 = edges[p + 8], e3 = edges[p + 12];
        float4 u0 = hpb[(size_t)(e0.x & 0x3FFFF) * 2 + half];
        float4 u1 = hpb[(size_t)(e1.x & 0x3FFFF) * 2 + half];
        float4 u2 = hpb[(size_t)(e2.x & 0x3FFFF) * 2 + half];
        float4 u3 = hpb[(size_t)(e3.x & 0x3FFFF) * 2 + half];
        fma_row8(u0, __int_as_float(e0.y), a, b);
        fma_row8(u1, __int_as_float(e1.y), a, b);
        fma_row8(u2, __int_as_float(e2.y), a, b);
        fma_row8(u3, __int_as_float(e3.y), a, b);
    }
    for (; p < end; p += 4) {
        int2 ev = edges[p];
        float4 u = hpb[(size_t)(ev.x & 0x3FFFF) * 2 + half];
        fma_row8(u, __int_as_float(ev.y), a, b);
    }
#pragma unroll
    for (int m = 2; m <= 4; m <<= 1) {
        a.x += __shfl_xor(a.x, m); a.y += __shfl_xor(a.y, m);
        a.z += __shfl_xor(a.z, m); a.w += __shfl_xor(a.w, m);
        b.x += __shfl_xor(b.x, m); b.y += __shfl_xor(b.y, m);
        b.z += __shfl_xor(b.z, m); b.w += __shfl_xor(b.w, m);
    }
    float di = dinv[i];
    float av[8] = { a.x*di, a.y*di, a.z*di, a.w*di,
                    b.x*di, b.y*di, b.z*di, b.w*di };
    int colBase = q * 10;
    float s[10];
#pragma unroll
    for (int c = 0; c < 10; ++c) {
        float acc = 0.0f;
#pragma unroll
        for (int j = 0; j < 8; ++j)
            acc = fmaf(av[j], sW2[(half * 8 + j) * NC + colBase + c], acc);
        s[c] = acc;
    }
#pragma unroll
    for (int c = 0; c < 10; ++c)
        s[c] += __shfl_xor(s[c], 1);   // combine the two feature halves
    // lane writes 5 columns
    float* op = out + (size_t)i * NC + colBase + half * 5;
#pragma unroll
    for (int c = 0; c < 5; ++c)
        op[c] = s[half * 5 + c] + sb2[colBase + half * 5 + c];
}

// ---- launch ----
extern "C" void kernel_launch(void* const* d_in, const int* in_sizes, int n_in,
                              void* d_out, int out_size, void* d_ws, size_t ws_size,
                              hipStream_t stream) {
    const float* x  = (const float*)d_in[0];
    const int*   ei = (const int*)d_in[1];
    const float* w  = (const float*)d_in[2];
    const float* W1 = (const float*)d_in[3];
    const float* b1 = (const float*)d_in[4];
    const float* W2 = (const float*)d_in[5];
    const float* b2 = (const float*)d_in[6];
    float* out = (float*)d_out;

    const int* src = ei;
    const int* dst = ei + NE;

    // workspace layout (4B words), ~72 MB.
    char* wsb = (char*)d_ws;
    float*   dinv      = (float*)  (wsb);                      // 200064
    int*     row_start = (int*)    (wsb + 200064LL * 4);       // 200064 (NN+1 used)
    int*     totals    = (int*)    (wsb + 400128LL * 4);       // 1024
    int*     binBase   = (int*)    (wsb + 401152LL * 4);       // 1024 (NBKT+1 used)
    int2*    ebuf      = (int2*)   (wsb + 402176LL * 4);       // NE int2 = 12.8M words
    __half2* hp        = (__half2*)(wsb + 13202176LL * 4);     // NN*8 half2 (1.6M words)
    int*     hist_g    = (int*)    (wsb + 13202176LL * 4);     // aliases hp region
    __half2* h1p       = (__half2*)(wsb + 14803776LL * 4);     // NN*8 half2 (1.6M words)
    int*     cnt_g     = (int*)    (wsb + 16405376LL * 4);     // 2048*782 words

    const int BN  = (NN + 255) / 256;   // 782
    const int BG8 = (8 * NN) / 256;     // 6250 exact

    k_chist   <<<NCHUNK, 256, 0, stream>>>(dst, hist_g, cnt_g);
    k_btotal  <<<NBKT, 256, 0, stream>>>(hist_g, totals);
    k_bscan   <<<1, 1024, 0, stream>>>(totals, binBase);
    k_cscan   <<<NBKT, 256, 0, stream>>>(hist_g, binBase);
    k_cscatter<<<SC_BLOCKS, 256, 0, stream>>>(src, dst, w, hist_g, cnt_g, ebuf);
    k_bsort   <<<NBKT, 256, 0, stream>>>(binBase, ebuf, dinv, row_start);
    k_gemm1   <<<BN, 256, 0, stream>>>(x, W1, dinv, hp);
    k_gather1 <<<BG8, 256, 0, stream>>>(row_start, ebuf, hp, dinv, b1, h1p);
    k_gather2 <<<BG8, 256, 0, stream>>>(row_start, ebuf, h1p, dinv, W2, b2, out);
}

// Round 16
// 398.940 us; speedup vs baseline: 1.0844x; 1.0368x over previous
//
#include <hip/hip_runtime.h>
#include <hip/hip_fp16.h>

#define NN 200000
#define NE 6400000
#define FIN 256
#define HID 16
#define NC 40
#define NBKT 782        // ceil(NN/256) dst-buckets of 256 nodes
#define NCHUNK 2048     // microchunks
#define EPC 3125        // edges per microchunk: 2048*3125 = 6.4M exact
#define CPT 8           // chunks per thread in btotal/cscan (2048/256)
#define SC_CHUNKS 2     // chunks per scatter block, processed SEQUENTIALLY
#define SC_BLOCKS (NCHUNK / SC_CHUNKS)  // 1024
#define STAGE_CAP 9472  // bucket stage capacity (mean 8192, ~14 sigma)

// ---- 1. per-microchunk coarse histogram over 782 dst-buckets (LDS atomics only) ----
__global__ __launch_bounds__(256) void k_chist(const int* __restrict__ dst,
                                               int* __restrict__ hist_g) {
    __shared__ int sh[NBKT];
    int c = blockIdx.x;
    for (int j = threadIdx.x; j < NBKT; j += 256) sh[j] = 0;
    __syncthreads();
    int beg = c * EPC;
    for (int e = beg + threadIdx.x; e < beg + EPC; e += 256)
        atomicAdd(&sh[dst[e] >> 8], 1);
    __syncthreads();
    for (int j = threadIdx.x; j < NBKT; j += 256)
        hist_g[c * NBKT + j] = sh[j];
}

// ---- 2. bucket totals: block per bucket, tree reduce over 2048 chunks ----
__global__ __launch_bounds__(256) void k_btotal(const int* __restrict__ hist_g,
                                                int* __restrict__ totals) {
    __shared__ int sm[256];
    int b = blockIdx.x, t = threadIdx.x;
    int s = 0;
#pragma unroll
    for (int j = 0; j < CPT; ++j)
        s += hist_g[(t * CPT + j) * NBKT + b];
    sm[t] = s;
    __syncthreads();
    for (int off = 128; off > 0; off >>= 1) {
        if (t < off) sm[t] += sm[t + off];
        __syncthreads();
    }
    if (t == 0) totals[b] = sm[0];
}

// ---- 3. exclusive scan of 782 totals -> binBase ----
__global__ __launch_bounds__(1024) void k_bscan(const int* __restrict__ totals,
                                                int* __restrict__ binBase) {
    __shared__ int sm[1024];
    int t = threadIdx.x;
    int v = (t < NBKT) ? totals[t] : 0;
    sm[t] = v;
    __syncthreads();
    for (int off = 1; off < 1024; off <<= 1) {
        int x = (t >= off) ? sm[t - off] : 0;
        __syncthreads();
        sm[t] += x;
        __syncthreads();
    }
    if (t < NBKT) binBase[t] = sm[t] - v;
    if (t == 0) binBase[NBKT] = NE;
}

// ---- 4. per-bucket scan over 2048 microchunks, in place: hist -> cursor bases ----
__global__ __launch_bounds__(256) void k_cscan(int* __restrict__ hist_g,
                                               const int* __restrict__ binBase) {
    __shared__ int sm[256];
    int b = blockIdx.x, t = threadIdx.x;
    int loc[CPT];
    int s = 0;
#pragma unroll
    for (int j = 0; j < CPT; ++j) {
        loc[j] = hist_g[(t * CPT + j) * NBKT + b];
        s += loc[j];
    }
    sm[t] = s;
    __syncthreads();
    for (int off = 1; off < 256; off <<= 1) {
        int x = (t >= off) ? sm[t - off] : 0;
        __syncthreads();
        sm[t] += x;
        __syncthreads();
    }
    int base = binBase[b] + sm[t] - s;
#pragma unroll
    for (int j = 0; j < CPT; ++j) {
        hist_g[(t * CPT + j) * NBKT + b] = base;
        base += loc[j];
    }
}

// ---- 5. coarse scatter: per-chunk counts derived as coff[c+1]-coff[c]
// (cscan is chunk-order cumulative; last chunk closes against binBase[j+1]).
// Bucket-id array filled at scan time (no binary search). 2 chunks sequential.
__global__ __launch_bounds__(256) void k_cscatter(const int* __restrict__ src,
                                                  const int* __restrict__ dst,
                                                  const float* __restrict__ w,
                                                  const int* __restrict__ coff,
                                                  const int* __restrict__ binBase,
                                                  int2* __restrict__ ebuf) {
    __shared__ int2 srec[EPC];                 // 25000 B sorted stage
    __shared__ unsigned short sbkt[EPC + 2];   // 6254 B bucket id per slot
    __shared__ int scur[NBKT];                 // rank cursors
    __shared__ int sgb[NBKT];                  // global base - local base
    __shared__ int sm[256];
    int t = threadIdx.x;
    for (int cc = 0; cc < SC_CHUNKS; ++cc) {
        int c = blockIdx.x * SC_CHUNKS + cc;
        int l[4], cv[4];
        int s = 0;
#pragma unroll
        for (int q = 0; q < 4; ++q) {
            int j = t * 4 + q;
            if (j < NBKT) {
                cv[q] = coff[c * NBKT + j];
                int nv = (c < NCHUNK - 1) ? coff[(c + 1) * NBKT + j]
                                          : binBase[j + 1];
                l[q] = nv - cv[q];
            } else { cv[q] = 0; l[q] = 0; }
            s += l[q];
        }
        sm[t] = s;
        __syncthreads();
        for (int off = 1; off < 256; off <<= 1) {
            int x = (t >= off) ? sm[t - off] : 0;
            __syncthreads();
            sm[t] += x;
            __syncthreads();
        }
        int base = sm[t] - s;
#pragma unroll
        for (int q = 0; q < 4; ++q) {
            int j = t * 4 + q;
            if (j < NBKT) {
                scur[j] = base;
                sgb[j]  = cv[q] - base;
                for (int u = 0; u < l[q]; ++u)       // fill bucket ids at scan
                    sbkt[base + u] = (unsigned short)j;
            }
            base += l[q];
        }
        __syncthreads();
        int beg = c * EPC;
        for (int e = beg + t; e < beg + EPC; e += 256) {
            int d = dst[e];
            int k = atomicAdd(&scur[d >> 8], 1);
            srec[k] = make_int2(src[e] | ((d & 255) << 18), __float_as_int(w[e]));
        }
        __syncthreads();
        for (int k = t; k < EPC; k += 256)
            ebuf[sgb[sbkt[k]] + k] = srec[k];
        __syncthreads();
    }
}

// ---- 6. fused per-bucket: stage once -> counts+deg -> scan -> dinv/row_start ->
//         rank -> direct ranked global store ----
__global__ __launch_bounds__(256) void k_bsort(const int* __restrict__ binBase,
                                               int2* __restrict__ ebuf,
                                               float* __restrict__ dinv,
                                               int* __restrict__ row_start) {
    __shared__ int2 stage[STAGE_CAP];   // 75776 B
    __shared__ float sdeg[256];
    __shared__ int scnt[256];
    __shared__ int ssc[256];
    int b = blockIdx.x, t = threadIdx.x;
    scnt[t] = 0;
    sdeg[t] = 1.0f;  // self-loop weight
    __syncthreads();
    int beg = binBase[b], end = binBase[b + 1];
    int cnt = end - beg;
    for (int j = t; j < cnt; j += 256) {
        int2 r = ebuf[beg + j];
        stage[j] = r;
        int dl = (r.x >> 18) & 255;
        atomicAdd(&scnt[dl], 1);
        atomicAdd(&sdeg[dl], __int_as_float(r.y));
    }
    __syncthreads();
    int node = b * 256 + t;
    if (node < NN) dinv[node] = rsqrtf(sdeg[t]);   // deg >= 1 always
    int v = scnt[t];
    ssc[t] = v;
    __syncthreads();
    for (int off = 1; off < 256; off <<= 1) {
        int x = (t >= off) ? ssc[t - off] : 0;
        __syncthreads();
        ssc[t] += x;
        __syncthreads();
    }
    int excl = ssc[t] - v;
    if (node < NN) row_start[node] = beg + excl;
    if (b == NBKT - 1 && t == 0) row_start[NN] = NE;
    scnt[t] = excl;
    __syncthreads();
    for (int j = t; j < cnt; j += 256) {
        int2 r = stage[j];
        int dl = (r.x >> 18) & 255;
        int k = atomicAdd(&scnt[dl], 1);
        ebuf[beg + k] = r;
    }
}

// ---- 7. h' = fp16( dinv[row] * (x @ W1) ), TWO 64B lines (8 float4s) in
// flight per macro-iter -> 2x outstanding loads vs r9 (was one line). ----
__global__ __launch_bounds__(256) void k_gemm1(const float* __restrict__ x,
                                               const float* __restrict__ W1,
                                               const float* __restrict__ dinv,
                                               __half2* __restrict__ hp) {
    int row = blockIdx.x * 256 + threadIdx.x;
    if (row >= NN) return;
    float acc[HID];
#pragma unroll
    for (int f = 0; f < HID; ++f) acc[f] = 0.0f;
    const float4* x4 = reinterpret_cast<const float4*>(x + (size_t)row * FIN);
    for (int kk = 0; kk < FIN / 4; kk += 8) {
        float4 v0 = x4[kk],     v1 = x4[kk + 1], v2 = x4[kk + 2], v3 = x4[kk + 3];
        float4 v4 = x4[kk + 4], v5 = x4[kk + 5], v6 = x4[kk + 6], v7 = x4[kk + 7];
        float xs[32] = { v0.x, v0.y, v0.z, v0.w, v1.x, v1.y, v1.z, v1.w,
                         v2.x, v2.y, v2.z, v2.w, v3.x, v3.y, v3.z, v3.w,
                         v4.x, v4.y, v4.z, v4.w, v5.x, v5.y, v5.z, v5.w,
                         v6.x, v6.y, v6.z, v6.w, v7.x, v7.y, v7.z, v7.w };
        int kbase = kk * 4;
#pragma unroll
        for (int j = 0; j < 32; ++j) {
            int k = kbase + j;   // wave-uniform -> W1 row via scalar K$ loads
#pragma unroll
            for (int f = 0; f < HID; ++f)
                acc[f] = fmaf(xs[j], W1[k * HID + f], acc[f]);
        }
    }
    float di = dinv[row];
    __half2 o[8];
#pragma unroll
    for (int j = 0; j < 8; ++j)
        o[j] = __floats2half2_rn(acc[2*j] * di, acc[2*j+1] * di);
    float4* st = reinterpret_cast<float4*>(hp + (size_t)row * 8);
    st[0] = *reinterpret_cast<float4*>(&o[0]);
    st[1] = *reinterpret_cast<float4*>(&o[4]);
}

// fp16 half-row (16B = 8 features) FMA into two float4 accumulators
__device__ __forceinline__ void fma_row8(const float4 u, float nv,
                                         float4& a, float4& b) {
    const __half2* h = reinterpret_cast<const __half2*>(&u);
    float2 f;
    f = __half22float2(h[0]); a.x = fmaf(f.x, nv, a.x); a.y = fmaf(f.y, nv, a.y);
    f = __half22float2(h[1]); a.z = fmaf(f.x, nv, a.z); a.w = fmaf(f.y, nv, a.w);
    f = __half22float2(h[2]); b.x = fmaf(f.x, nv, b.x); b.y = fmaf(f.y, nv, b.y);
    f = __half22float2(h[3]); b.z = fmaf(f.x, nv, b.z); b.w = fmaf(f.y, nv, b.w);
}

union H4F4 { __half2 h[4]; float4 f; };

// ---- 8. gather layer 1: 8 lanes/node, lane-pairs share each edge (one 32B
// coalesced transaction per edge row). ----
__global__ __launch_bounds__(256) void k_gather1(const int* __restrict__ row_start,
                                                 const int2* __restrict__ edges,
                                                 const __half2* __restrict__ hp,
                                                 const float* __restrict__ dinv,
                                                 const float* __restrict__ b1,
                                                 __half2* __restrict__ h1p) {
    int t = blockIdx.x * 256 + threadIdx.x;   // grid exact: 8*NN threads
    int i = t >> 3;
    int l3 = t & 7;
    int q = l3 >> 1;      // pair 0..3: edge subset
    int half = l3 & 1;    // which 16B half of the row this lane loads
    int beg = row_start[i];
    int end = row_start[i + 1];
    const float4* hpb = reinterpret_cast<const float4*>(hp);
    float4 a = make_float4(0.f,0.f,0.f,0.f), b = a;
    if (q == 0)
        fma_row8(hpb[(size_t)i * 2 + half], 1.0f, a, b);
    int p = beg + q;
    for (; p + 12 < end; p += 16) {
        int2 e0 = edges[p], e1 = edges[p + 4], e2 = edges[p + 8], e3 = edges[p + 12];
        float4 u0 = hpb[(size_t)(e0.x & 0x3FFFF) * 2 + half];
        float4 u1 = hpb[(size_t)(e1.x & 0x3FFFF) * 2 + half];
        float4 u2 = hpb[(size_t)(e2.x & 0x3FFFF) * 2 + half];
        float4 u3 = hpb[(size_t)(e3.x & 0x3FFFF) * 2 + half];
        fma_row8(u0, __int_as_float(e0.y), a, b);
        fma_row8(u1, __int_as_float(e1.y), a, b);
        fma_row8(u2, __int_as_float(e2.y), a, b);
        fma_row8(u3, __int_as_float(e3.y), a, b);
    }
    for (; p < end; p += 4) {
        int2 ev = edges[p];
        float4 u = hpb[(size_t)(ev.x & 0x3FFFF) * 2 + half];
        fma_row8(u, __int_as_float(ev.y), a, b);
    }
#pragma unroll
    for (int m = 2; m <= 4; m <<= 1) {
        a.x += __shfl_xor(a.x, m); a.y += __shfl_xor(a.y, m);
        a.z += __shfl_xor(a.z, m); a.w += __shfl_xor(a.w, m);
        b.x += __shfl_xor(b.x, m); b.y += __shfl_xor(b.y, m);
        b.z += __shfl_xor(b.z, m); b.w += __shfl_xor(b.w, m);
    }
    float di = dinv[i];
    float4 b1a = reinterpret_cast<const float4*>(b1)[half * 2];
    float4 b1b = reinterpret_cast<const float4*>(b1)[half * 2 + 1];
    a.x = di * fmaxf(fmaf(di, a.x, b1a.x), 0.f);
    a.y = di * fmaxf(fmaf(di, a.y, b1a.y), 0.f);
    a.z = di * fmaxf(fmaf(di, a.z, b1a.z), 0.f);
    a.w = di * fmaxf(fmaf(di, a.w, b1a.w), 0.f);
    b.x = di * fmaxf(fmaf(di, b.x, b1b.x), 0.f);
    b.y = di * fmaxf(fmaf(di, b.y, b1b.y), 0.f);
    b.z = di * fmaxf(fmaf(di, b.z, b1b.z), 0.f);
    b.w = di * fmaxf(fmaf(di, b.w, b1b.w), 0.f);
    if (q == 0) {
        H4F4 pk;
        pk.h[0] = __floats2half2_rn(a.x, a.y);
        pk.h[1] = __floats2half2_rn(a.z, a.w);
        pk.h[2] = __floats2half2_rn(b.x, b.y);
        pk.h[3] = __floats2half2_rn(b.z, b.w);
        reinterpret_cast<float4*>(h1p)[(size_t)i * 2 + half] = pk.f;
    }
}

// ---- 9. gather layer 2 fused with GEMM2, 8 lanes/node pair scheme ----
__global__ __launch_bounds__(256) void k_gather2(const int* __restrict__ row_start,
                                                 const int2* __restrict__ edges,
                                                 const __half2* __restrict__ h1p,
                                                 const float* __restrict__ dinv,
                                                 const float* __restrict__ W2,
                                                 const float* __restrict__ b2,
                                                 float* __restrict__ out) {
    __shared__ float sW2[HID * NC];
    __shared__ float sb2[NC];
    {
        int tt = threadIdx.x;
        for (int j = tt; j < HID * NC; j += 256) sW2[j] = W2[j];
        if (tt < NC) sb2[tt] = b2[tt];
    }
    __syncthreads();
    int t = blockIdx.x * 256 + threadIdx.x;   // grid exact: 8*NN threads
    int i = t >> 3;
    int l3 = t & 7;
    int q = l3 >> 1;
    int half = l3 & 1;
    int beg = row_start[i];
    int end = row_start[i + 1];
    const float4* hpb = reinterpret_cast<const float4*>(h1p);
    float4 a = make_float4(0.f,0.f,0.f,0.f), b = a;
    if (q == 0)
        fma_row8(hpb[(size_t)i * 2 + half], 1.0f, a, b);
    int p = beg + q;
    for (; p + 12 < end; p += 16) {
        int2 e0 = edges[p], e1 = edges[p + 4], e2 = edges[p + 8], e3 = edges[p + 12];
        float4 u0 = hpb[(size_t)(e0.x & 0x3FFFF) * 2 + half];
        float4 u1 = hpb[(size_t)(e1.x & 0x3FFFF) * 2 + half];
        float4 u2 = hpb[(size_t)(e2.x & 0x3FFFF) * 2 + half];
        float4 u3 = hpb[(size_t)(e3.x & 0x3FFFF) * 2 + half];
        fma_row8(u0, __int_as_float(e0.y), a, b);
        fma_row8(u1, __int_as_float(e1.y), a, b);
        fma_row8(u2, __int_as_float(e2.y), a, b);
        fma_row8(u3, __int_as_float(e3.y), a, b);
    }
    for (; p < end; p += 4) {
        int2 ev = edges[p];
        float4 u = hpb[(size_t)(ev.x & 0x3FFFF) * 2 + half];
        fma_row8(u, __int_as_float(ev.y), a, b);
    }
#pragma unroll
    for (int m = 2; m <= 4; m <<= 1) {
        a.x += __shfl_xor(a.x, m); a.y += __shfl_xor(a.y, m);
        a.z += __shfl_xor(a.z, m); a.w += __shfl_xor(a.w, m);
        b.x += __shfl_xor(b.x, m); b.y += __shfl_xor(b.y, m);
        b.z += __shfl_xor(b.z, m); b.w += __shfl_xor(b.w, m);
    }
    float di = dinv[i];
    float av[8] = { a.x*di, a.y*di, a.z*di, a.w*di,
                    b.x*di, b.y*di, b.z*di, b.w*di };
    int colBase = q * 10;
    float s[10];
#pragma unroll
    for (int c = 0; c < 10; ++c) {
        float acc = 0.0f;
#pragma unroll
        for (int j = 0; j < 8; ++j)
            acc = fmaf(av[j], sW2[(half * 8 + j) * NC + colBase + c], acc);
        s[c] = acc;
    }
#pragma unroll
    for (int c = 0; c < 10; ++c)
        s[c] += __shfl_xor(s[c], 1);
    float* op = out + (size_t)i * NC + colBase + half * 5;
#pragma unroll
    for (int c = 0; c < 5; ++c)
        op[c] = s[half * 5 + c] + sb2[colBase + half * 5 + c];
}

// ---- launch ----
extern "C" void kernel_launch(void* const* d_in, const int* in_sizes, int n_in,
                              void* d_out, int out_size, void* d_ws, size_t ws_size,
                              hipStream_t stream) {
    const float* x  = (const float*)d_in[0];
    const int*   ei = (const int*)d_in[1];
    const float* w  = (const float*)d_in[2];
    const float* W1 = (const float*)d_in[3];
    const float* b1 = (const float*)d_in[4];
    const float* W2 = (const float*)d_in[5];
    const float* b2 = (const float*)d_in[6];
    float* out = (float*)d_out;

    const int* src = ei;
    const int* dst = ei + NE;

    // workspace layout (4B words), ~66 MB.
    // hp (fp16 rows) shares its region with hist_g (dead after k_cscatter;
    // hp first written by k_gemm1, later in stream order).
    char* wsb = (char*)d_ws;
    float*   dinv      = (float*)  (wsb);                      // 200064
    int*     row_start = (int*)    (wsb + 200064LL * 4);       // 200064 (NN+1 used)
    int*     totals    = (int*)    (wsb + 400128LL * 4);       // 1024
    int*     binBase   = (int*)    (wsb + 401152LL * 4);       // 1024 (NBKT+1 used)
    int2*    ebuf      = (int2*)   (wsb + 402176LL * 4);       // NE int2 = 12.8M words
    __half2* hp        = (__half2*)(wsb + 13202176LL * 4);     // NN*8 half2 (1.6M words)
    int*     hist_g    = (int*)    (wsb + 13202176LL * 4);     // aliases hp region
    __half2* h1p       = (__half2*)(wsb + 14803776LL * 4);     // NN*8 half2 (1.6M words)

    const int BN  = (NN + 255) / 256;   // 782
    const int BG8 = (8 * NN) / 256;     // 6250 exact

    k_chist   <<<NCHUNK, 256, 0, stream>>>(dst, hist_g);
    k_btotal  <<<NBKT, 256, 0, stream>>>(hist_g, totals);
    k_bscan   <<<1, 1024, 0, stream>>>(totals, binBase);
    k_cscan   <<<NBKT, 256, 0, stream>>>(hist_g, binBase);
    k_cscatter<<<SC_BLOCKS, 256, 0, stream>>>(src, dst, w, hist_g, binBase, ebuf);
    k_bsort   <<<NBKT, 256, 0, stream>>>(binBase, ebuf, dinv, row_start);
    k_gemm1   <<<BN, 256, 0, stream>>>(x, W1, dinv, hp);
    k_gather1 <<<BG8, 256, 0, stream>>>(row_start, ebuf, hp, dinv, b1, h1p);
    k_gather2 <<<BG8, 256, 0, stream>>>(row_start, ebuf, h1p, dinv, W2, b2, out);
}